// Round 9
// baseline (217.786 us; speedup 1.0000x reference)
//
#include <hip/hip_runtime.h>
#include <hip/hip_fp16.h>

typedef _Float16 half8 __attribute__((ext_vector_type(8)));
typedef float    f32x4 __attribute__((ext_vector_type(4)));
typedef float    f32x2 __attribute__((ext_vector_type(2)));

#define EPSL 0.1f
#define TWO_LOG2E 2.8853900817779268f  // 2*log2(e): exp(2z) = exp2(z*TWO_LOG2E)
#define NT 2                           // sample-tiles per wave-iteration (32 samples)

#if __has_builtin(__builtin_amdgcn_exp2f)
#define EXP2(x) __builtin_amdgcn_exp2f(x)
#else
#define EXP2(x) __expf((x) * 0.6931471805599453f)
#endif

// tanh for a packed pair; input y = z * TWO_LOG2E (pre-scaled so the only
// scalar ops are the two quarter-rate trans insts; all glue is v_pk_*_f32).
__device__ __forceinline__ f32x2 tanh2s(f32x2 y) {
    f32x2 e;
    e.x = EXP2(y.x);
    e.y = EXP2(y.y);
    const f32x2 ep = e + 1.0f;                 // v_pk_add_f32
    f32x2 r;
    r.x = __builtin_amdgcn_rcpf(ep.x);
    r.y = __builtin_amdgcn_rcpf(ep.y);
    return 1.0f - 2.0f * r;                    // v_pk_fma_f32
}

// v_cvt_pkrtz_f16_f32: pack two f32 into one uint (lo=a, hi=b), 1 inst.
__device__ __forceinline__ unsigned int pk2(float a, float b) {
    union { __fp16 __attribute__((ext_vector_type(2))) h; unsigned int u; } v;
    v.h = __builtin_amdgcn_cvt_pkrtz(a, b);
    return v.u;
}
__device__ __forceinline__ f32x2 unpk2v(unsigned int u) {
    union { unsigned int u; __half2 h; } v; v.u = u;
    const float2 f = __half22float2(v.h);
    return (f32x2){f.x, f.y};
}
__device__ __forceinline__ f32x2 lo2(f32x4 v) { return __builtin_shufflevector(v, v, 0, 1); }
__device__ __forceinline__ f32x2 hi2(f32x4 v) { return __builtin_shufflevector(v, v, 2, 3); }

union frag_u { unsigned int u[4]; half8 h; };

// Feature-major (transposed) orientation: every GEMM is  C = W_frag(A) x actT(B),
// with samples in the N dim (one 16-wide tile = 16 samples).
// C layout: (feature-row = 4q+g in tile mt, sample-col = r).  The NEXT GEMM's
// B-frag wants (k-slot (kt,q,j), sample r).  Baking the K-permutation
//    pi(kt,q,j) = (2*kt + (j>>2))*16 + 4q + (j&3)
// into the packed A-operand makes the producer's own registers BE the B-frag
// -> zero cross-lane ops, zero LDS dataflow, zero barriers between all 4 GEMMs.
//
// mat 0: GEMM1  z1T = W1T @ h0T   A[m=f1=mt*16+r][k=f0=kt*32+8q+j]      = W1[f0][f1]
// mat 1: GEMM2  z2T = W2T @ h1T   A[m=f2=mt*16+r][k=pi->f1]             = W2[f1][f2]
// mat 2: GEMM3  g1T = W2  @ dz2T  A[m=f1=mt*16+r][k=pi->f2]             = W2[f1][f2]
// mat 3: GEMM4  g0T = W1  @ dz1T  A[m=sigma(mt,r)][k=pi->f1]            = W1[f0][f1]
//        sigma(mt,r) = (mt&1)*32 + 8*(r>>2) + ((mt>>1)&1)*4 + (r&3)  puts each
//        lane's GEMM4 outputs on the h0 features it already holds from P0.
// stored lane-contiguous: pk[((mat*2+kt)*4+mt)*512 + lane*8 + j].
__global__ void pack_weights(const float* __restrict__ W1,
                             const float* __restrict__ W2,
                             _Float16* __restrict__ pk) {
    const int t = threadIdx.x;            // 0..63
    const int combo = blockIdx.x;         // ((mat*2+kt)*4+mt), 0..31
    const int mt  = combo & 3;
    const int kt  = (combo >> 2) & 1;
    const int mat = combo >> 3;
    const int q = t >> 4, r = t & 15;
    _Float16 v[8];
    #pragma unroll
    for (int j = 0; j < 8; ++j) {
        const int fk = (2 * kt + (j >> 2)) * 16 + 4 * q + (j & 3);   // pi(kt,q,j)
        float x;
        if (mat == 0)      x = W1[(kt * 32 + 8 * q + j) * 64 + mt * 16 + r];
        else if (mat == 1) x = W2[fk * 64 + mt * 16 + r];
        else if (mat == 2) x = W2[(mt * 16 + r) * 64 + fk];
        else {
            const int f0 = (mt & 1) * 32 + 8 * (r >> 2) + ((mt >> 1) & 1) * 4 + (r & 3);
            x = W1[f0 * 64 + fk];
        }
        v[j] = (_Float16)x;
    }
    *(half8*)(pk + combo * 512 + t * 8) = *(const half8*)v;
}

// PERSISTENT WAVES: R7 showed the NT-sweep is a parabola (177/151/165 at
// NT=1/2/4) and every wave previously lived for ONE tile-group — paying a
// full serial prologue (x, W0/b, 32 ldpk loads at ~200cy L2 latency) per 32
// samples with too few waves to hide it. Now: grid = 768 blocks (3/CU),
// each wave grid-strides over ~10.7 tile-groups. Weight loads become
// loop-invariant (LICM) and iterations software-pipeline (next x-load and
// ldpk issue while previous P4 computes).
// Occupancy pinning (R2-R7 evidence: RA budget = LDS-derived): 52KB pad ->
// 3 blocks/CU -> 3 waves/EU -> VGPR cap ~170 >= demand (~150).
// (R8 run of this exact source died to an infra "container failed twice"
// error before producing any signal — resubmitted unchanged.)
extern "C" __global__ void __launch_bounds__(256)
lnn_mfma(const float* __restrict__ x,
         const float* __restrict__ W0, const float* __restrict__ b0,
         const float* __restrict__ b1, const float* __restrict__ b2,
         const float* __restrict__ W3,
         const _Float16* __restrict__ pk,
         float* __restrict__ out,
         int ntask)
{
    __shared__ float occ_pad[13312];   // 52 KB, never touched at runtime
    if (blockIdx.x == 0xFFFFFFFFu) ((volatile float*)occ_pad)[threadIdx.x] = 1.0f;

    const int t = threadIdx.x & 63;
    const int q = t >> 4;
    const int r = t & 15;
    const int wgid = blockIdx.x * 4 + (threadIdx.x >> 6);
    const int nw   = gridDim.x * 4;

    auto ldpk = [&](int mat, int kt, int mt) -> half8 {
        return *(const half8*)(pk + ((mat * 2 + kt) * 4 + mt) * 512 + t * 8);
    };

    // W0 pair-tables + b0, shared by P0 and P4 — loop-invariant (lane-only).
    f32x2 wa2[2][4], wb2[2][4], bb2[2][4];
    #pragma unroll
    for (int kt = 0; kt < 2; ++kt) {
        const int f = kt * 32 + q * 8;
        const float4 waA = *(const float4*)(W0 + f);
        const float4 waB = *(const float4*)(W0 + f + 4);
        const float4 wbA = *(const float4*)(W0 + 64 + f);
        const float4 wbB = *(const float4*)(W0 + 64 + f + 4);
        const float4 bbA = *(const float4*)(b0 + f);
        const float4 bbB = *(const float4*)(b0 + f + 4);
        wa2[kt][0] = (f32x2){waA.x, waA.y}; wa2[kt][1] = (f32x2){waA.z, waA.w};
        wa2[kt][2] = (f32x2){waB.x, waB.y}; wa2[kt][3] = (f32x2){waB.z, waB.w};
        wb2[kt][0] = (f32x2){wbA.x, wbA.y}; wb2[kt][1] = (f32x2){wbA.z, wbA.w};
        wb2[kt][2] = (f32x2){wbB.x, wbB.y}; wb2[kt][3] = (f32x2){wbB.z, wbB.w};
        bb2[kt][0] = (f32x2){bbA.x, bbA.y}; bb2[kt][1] = (f32x2){bbA.z, bbA.w};
        bb2[kt][2] = (f32x2){bbB.x, bbB.y}; bb2[kt][3] = (f32x2){bbB.z, bbB.w};
    }

    for (int task = wgid; task < ntask; task += nw) {
        const long sbase = (long)task * (16 * NT);

        float x0v[NT], x1v[NT];
        #pragma unroll
        for (int u = 0; u < NT; ++u) {
            const float2 xv = *(const float2*)(x + 2 * (sbase + u * 16 + r));
            x0v[u] = xv.x; x1v[u] = xv.y;
        }

        // ---------------- P0: h0/th0 as GEMM1 B-frags (k=f0=kt*32+8q+j, n=r).
        half8 ah0[NT][2], at0[NT][2];          // [u][kt]
        #pragma unroll
        for (int kt = 0; kt < 2; ++kt)
            #pragma unroll
            for (int u = 0; u < NT; ++u) {
                union { unsigned int uu[4]; half8 h; } ph, pt;
                #pragma unroll
                for (int p = 0; p < 4; ++p) {
                    const f32x2 z = x0v[u] * wa2[kt][p] + x1v[u] * wb2[kt][p] + bb2[kt][p];
                    const f32x2 h = tanh2s(z * TWO_LOG2E);
                    const f32x2 A = 1.0f - h * h;
                    const f32x2 tt = A * wb2[kt][p];
                    ph.uu[p] = pk2(h.x, h.y);
                    pt.uu[p] = pk2(tt.x, tt.y);
                }
                ah0[u][kt] = ph.h; at0[u][kt] = pt.h;
            }

        // ---------------- GEMM1: z1T = W1T @ h0T  (+b1 in acc init)
        f32x4 acc[NT][4], tacc[NT][4];         // [u][mt]
        #pragma unroll
        for (int mt = 0; mt < 4; ++mt) {
            const f32x4 bv = *(const f32x4*)(b1 + mt * 16 + 4 * q);   // f1 = mt*16+4q+g
            #pragma unroll
            for (int u = 0; u < NT; ++u) {
                acc[u][mt] = bv;
                tacc[u][mt] = (f32x4){0,0,0,0};
            }
        }
        #pragma unroll
        for (int kt = 0; kt < 2; ++kt)
            #pragma unroll
            for (int mt = 0; mt < 4; ++mt) {
                const half8 aw = ldpk(0, kt, mt);      // shared by all tiles
                #pragma unroll
                for (int u = 0; u < NT; ++u) {
                    acc[u][mt]  = __builtin_amdgcn_mfma_f32_16x16x32_f16(aw, ah0[u][kt], acc[u][mt], 0, 0, 0);
                    tacc[u][mt] = __builtin_amdgcn_mfma_f32_16x16x32_f16(aw, at0[u][kt], tacc[u][mt], 0, 0, 0);
                }
            }

        // ---------------- P1: h1/th1 -> directly into GEMM2 B-frag words.
        // Also doubles as the h1 store P3 reads back (same positions).
        frag_u bh1[NT][2], bt1[NT][2];         // [u][kt]
        #pragma unroll
        for (int u = 0; u < NT; ++u)
            #pragma unroll
            for (int mt = 0; mt < 4; ++mt) {
                const f32x2 zp[2] = {lo2(acc[u][mt]),  hi2(acc[u][mt])};
                const f32x2 tp[2] = {lo2(tacc[u][mt]), hi2(tacc[u][mt])};
                #pragma unroll
                for (int p = 0; p < 2; ++p) {
                    const f32x2 h  = tanh2s(zp[p] * TWO_LOG2E);
                    const f32x2 A  = 1.0f - h * h;
                    const f32x2 th = A * tp[p];
                    bh1[u][mt >> 1].u[2 * (mt & 1) + p] = pk2(h.x, h.y);
                    bt1[u][mt >> 1].u[2 * (mt & 1) + p] = pk2(th.x, th.y);
                }
            }

        // ---------------- GEMM2: z2T = W2T @ h1T  (+b2 in acc init)
        #pragma unroll
        for (int mt = 0; mt < 4; ++mt) {
            const f32x4 bv = *(const f32x4*)(b2 + mt * 16 + 4 * q);
            #pragma unroll
            for (int u = 0; u < NT; ++u) {
                acc[u][mt] = bv;
                tacc[u][mt] = (f32x4){0,0,0,0};
            }
        }
        #pragma unroll
        for (int kt = 0; kt < 2; ++kt)
            #pragma unroll
            for (int mt = 0; mt < 4; ++mt) {
                const half8 aw = ldpk(1, kt, mt);
                #pragma unroll
                for (int u = 0; u < NT; ++u) {
                    acc[u][mt]  = __builtin_amdgcn_mfma_f32_16x16x32_f16(aw, bh1[u][kt].h, acc[u][mt], 0, 0, 0);
                    tacc[u][mt] = __builtin_amdgcn_mfma_f32_16x16x32_f16(aw, bt1[u][kt].h, tacc[u][mt], 0, 0, 0);
                }
            }

        // ---------------- P2: dz2 = W3*A2 ; tdz2 = -2*h2*dz2*tz2 -> GEMM3 B-frags
        frag_u bh2[NT][2], bt2[NT][2];
        #pragma unroll
        for (int mt = 0; mt < 4; ++mt) {
            const float4 w3v = *(const float4*)(W3 + mt * 16 + 4 * q);
            const f32x2 w3p[2] = {{w3v.x, w3v.y}, {w3v.z, w3v.w}};
            #pragma unroll
            for (int u = 0; u < NT; ++u) {
                const f32x2 zp[2] = {lo2(acc[u][mt]),  hi2(acc[u][mt])};
                const f32x2 tp[2] = {lo2(tacc[u][mt]), hi2(tacc[u][mt])};
                #pragma unroll
                for (int p = 0; p < 2; ++p) {
                    const f32x2 h  = tanh2s(zp[p] * TWO_LOG2E);
                    const f32x2 A  = 1.0f - h * h;
                    const f32x2 dz = A * w3p[p];
                    const f32x2 t1 = h * tp[p];
                    const f32x2 td = -2.0f * (dz * t1);
                    bh2[u][mt >> 1].u[2 * (mt & 1) + p] = pk2(dz.x, dz.y);
                    bt2[u][mt >> 1].u[2 * (mt & 1) + p] = pk2(td.x, td.y);
                }
            }
        }

        // ---------------- GEMM3: g1T = W2 @ dz2T
        #pragma unroll
        for (int u = 0; u < NT; ++u)
            #pragma unroll
            for (int mt = 0; mt < 4; ++mt) { acc[u][mt] = (f32x4){0,0,0,0}; tacc[u][mt] = (f32x4){0,0,0,0}; }
        #pragma unroll
        for (int kt = 0; kt < 2; ++kt)
            #pragma unroll
            for (int mt = 0; mt < 4; ++mt) {
                const half8 aw = ldpk(2, kt, mt);
                #pragma unroll
                for (int u = 0; u < NT; ++u) {
                    acc[u][mt]  = __builtin_amdgcn_mfma_f32_16x16x32_f16(aw, bh2[u][kt].h, acc[u][mt], 0, 0, 0);
                    tacc[u][mt] = __builtin_amdgcn_mfma_f32_16x16x32_f16(aw, bt2[u][kt].h, tacc[u][mt], 0, 0, 0);
                }
            }

        // ---------------- P3: dz1 = g1*A1 ; tdz1 = tg1*A1 - 2*g1*h1*th1
        // h1/th1 read straight back from bh1/bt1 (same (u,mt,p) positions).
        frag_u bd[NT][2], btd[NT][2];
        #pragma unroll
        for (int u = 0; u < NT; ++u)
            #pragma unroll
            for (int mt = 0; mt < 4; ++mt) {
                const f32x2 gp[2] = {lo2(acc[u][mt]),  hi2(acc[u][mt])};
                const f32x2 tp[2] = {lo2(tacc[u][mt]), hi2(tacc[u][mt])};
                #pragma unroll
                for (int p = 0; p < 2; ++p) {
                    const f32x2 h  = unpk2v(bh1[u][mt >> 1].u[2 * (mt & 1) + p]);
                    const f32x2 th = unpk2v(bt1[u][mt >> 1].u[2 * (mt & 1) + p]);
                    const f32x2 A  = 1.0f - h * h;
                    const f32x2 d1 = gp[p] * A;
                    const f32x2 u2 = (gp[p] * h) * th;
                    const f32x2 td = tp[p] * A + (-2.0f) * u2;
                    bd[u][mt >> 1].u[2 * (mt & 1) + p]  = pk2(d1.x, d1.y);
                    btd[u][mt >> 1].u[2 * (mt & 1) + p] = pk2(td.x, td.y);
                }
            }

        // ---------------- GEMM4: g0T = W1(sigma-rows) @ dz1T
        #pragma unroll
        for (int u = 0; u < NT; ++u)
            #pragma unroll
            for (int mt = 0; mt < 4; ++mt) { acc[u][mt] = (f32x4){0,0,0,0}; tacc[u][mt] = (f32x4){0,0,0,0}; }
        #pragma unroll
        for (int kt = 0; kt < 2; ++kt)
            #pragma unroll
            for (int mt = 0; mt < 4; ++mt) {
                const half8 aw = ldpk(3, kt, mt);
                #pragma unroll
                for (int u = 0; u < NT; ++u) {
                    acc[u][mt]  = __builtin_amdgcn_mfma_f32_16x16x32_f16(aw, bd[u][kt].h,  acc[u][mt], 0, 0, 0);
                    tacc[u][mt] = __builtin_amdgcn_mfma_f32_16x16x32_f16(aw, btd[u][kt].h, tacc[u][mt], 0, 0, 0);
                }
            }

        // ---------------- P4: with sigma, acc[u][mt][g] is the gradient for feature
        //   f0 = (mt&1)*32 + 8q + (mt>>1)*4 + g  — i.e. ah0[u][mt&1] word j2+p,
        //   and W0 pairs wa2[kt][j2+p] (reused from P0's tables — no reload).
        f32x2 pg2[NT], ph02[NT], ph12[NT];
        #pragma unroll
        for (int u = 0; u < NT; ++u) { pg2[u] = (f32x2){0,0}; ph02[u] = (f32x2){0,0}; ph12[u] = (f32x2){0,0}; }
        #pragma unroll
        for (int mt = 0; mt < 4; ++mt) {
            const int kt = mt & 1;
            const int j2 = ((mt >> 1) & 1) * 2;          // pair base: 0 or 2
            #pragma unroll
            for (int u = 0; u < NT; ++u) {
                union { half8 h; unsigned int uu[4]; } av; av.h = ah0[u][kt];
                const unsigned int hu[2] = {av.uu[j2], av.uu[j2 + 1]};
                const f32x2 gp[2] = {lo2(acc[u][mt]),  hi2(acc[u][mt])};
                const f32x2 tp[2] = {lo2(tacc[u][mt]), hi2(tacc[u][mt])};
                #pragma unroll
                for (int p = 0; p < 2; ++p) {
                    const f32x2 h   = unpk2v(hu[p]);     // features f+2p, f+2p+1
                    const f32x2 A   = 1.0f - h * h;
                    const f32x2 th0 = A * wb2[kt][j2 + p];
                    const f32x2 d0  = gp[p] * A;
                    const f32x2 u2  = (gp[p] * h) * th0;
                    const f32x2 td0 = tp[p] * A + (-2.0f) * u2;
                    pg2[u]  += wa2[kt][j2 + p] * d0;
                    ph02[u] += wa2[kt][j2 + p] * td0;
                    ph12[u] += wb2[kt][j2 + p] * td0;
                }
            }
        }
        #pragma unroll
        for (int u = 0; u < NT; ++u) {
            float pg  = pg2[u].x  + pg2[u].y;
            float ph0 = ph02[u].x + ph02[u].y;
            float ph1 = ph12[u].x + ph12[u].y;
            pg  += __shfl_xor(pg, 16);  pg  += __shfl_xor(pg, 32);
            ph0 += __shfl_xor(ph0, 16); ph0 += __shfl_xor(ph0, 32);
            ph1 += __shfl_xor(ph1, 16); ph1 += __shfl_xor(ph1, 32);
            if (q == 0) {
                const float num = fmaf(-ph0, x1v[u], pg);
                const float den = ph1 + EPSL;
                const float a = num * __builtin_amdgcn_rcpf(den);
                float2 o;
                o.x = x1v[u];
                o.y = a;
                *(float2*)(out + 2 * (sbase + u * 16 + r)) = o;
            }
        }
    }
}

extern "C" void kernel_launch(void* const* d_in, const int* in_sizes, int n_in,
                              void* d_out, int out_size, void* d_ws, size_t ws_size,
                              hipStream_t stream) {
    // setup_inputs order: t, x, W0, b0, W1, b1, W2, b2, W3, b3
    const float* x  = (const float*)d_in[1];
    const float* W0 = (const float*)d_in[2];
    const float* b0 = (const float*)d_in[3];
    const float* W1 = (const float*)d_in[4];
    const float* b1 = (const float*)d_in[5];
    const float* W2 = (const float*)d_in[6];
    const float* b2 = (const float*)d_in[7];
    const float* W3 = (const float*)d_in[8];
    // b3 unused (no effect on grad/Hessian)

    _Float16* pk = (_Float16*)d_ws;   // 4 mats * 4096 halfs = 32 KB
    const int B = in_sizes[1] / 2;    // 1048576
    const int ntask = B / (16 * NT);  // 32768 wave-tasks of 32 samples

    pack_weights<<<32, 64, 0, stream>>>(W1, W2, pk);
    // Persistent: 768 blocks = 3/CU exactly; 3072 waves x ~10.7 iterations.
    lnn_mfma<<<768, 256, 0, stream>>>(x, W0, b0, b1, b2, W3, pk, (float*)d_out, ntask);
}

// Round 10
// 200.307 us; speedup vs baseline: 1.0873x; 1.0873x over previous
//
#include <hip/hip_runtime.h>
#include <hip/hip_fp16.h>

typedef _Float16 half8 __attribute__((ext_vector_type(8)));
typedef float    f32x4 __attribute__((ext_vector_type(4)));
typedef float    f32x2 __attribute__((ext_vector_type(2)));

#define EPSL 0.1f
#define TWO_LOG2E 2.8853900817779268f  // 2*log2(e): exp(2z) = exp2(z*TWO_LOG2E)
#define NT 2                           // sample-tiles per wave (32 samples) — R6 optimum

#if __has_builtin(__builtin_amdgcn_exp2f)
#define EXP2(x) __builtin_amdgcn_exp2f(x)
#else
#define EXP2(x) __expf((x) * 0.6931471805599453f)
#endif

// tanh for a packed pair; input y = z * TWO_LOG2E (pre-scaled so the only
// scalar ops are the two quarter-rate trans insts; all glue is v_pk_*_f32).
__device__ __forceinline__ f32x2 tanh2s(f32x2 y) {
    f32x2 e;
    e.x = EXP2(y.x);
    e.y = EXP2(y.y);
    const f32x2 ep = e + 1.0f;                 // v_pk_add_f32
    f32x2 r;
    r.x = __builtin_amdgcn_rcpf(ep.x);
    r.y = __builtin_amdgcn_rcpf(ep.y);
    return 1.0f - 2.0f * r;                    // v_pk_fma_f32
}

// v_cvt_pkrtz_f16_f32: pack two f32 into one uint (lo=a, hi=b), 1 inst.
__device__ __forceinline__ unsigned int pk2(float a, float b) {
    union { __fp16 __attribute__((ext_vector_type(2))) h; unsigned int u; } v;
    v.h = __builtin_amdgcn_cvt_pkrtz(a, b);
    return v.u;
}
__device__ __forceinline__ f32x2 unpk2v(unsigned int u) {
    union { unsigned int u; __half2 h; } v; v.u = u;
    const float2 f = __half22float2(v.h);
    return (f32x2){f.x, f.y};
}
__device__ __forceinline__ f32x2 lo2(f32x4 v) { return __builtin_shufflevector(v, v, 0, 1); }
__device__ __forceinline__ f32x2 hi2(f32x4 v) { return __builtin_shufflevector(v, v, 2, 3); }

union frag_u { unsigned int u[4]; half8 h; };

// Feature-major (transposed) orientation: every GEMM is  C = W_frag(A) x actT(B),
// with samples in the N dim (one 16-wide tile = 16 samples).
// C layout: (feature-row = 4q+g in tile mt, sample-col = r).  The NEXT GEMM's
// B-frag wants (k-slot (kt,q,j), sample r).  Baking the K-permutation
//    pi(kt,q,j) = (2*kt + (j>>2))*16 + 4q + (j&3)
// into the packed A-operand makes the producer's own registers BE the B-frag
// -> zero cross-lane ops, zero LDS dataflow, zero barriers between all 4 GEMMs.
//
// mat 0: GEMM1  z1T = W1T @ h0T   A[m=f1=mt*16+r][k=f0=kt*32+8q+j]      = W1[f0][f1]
// mat 1: GEMM2  z2T = W2T @ h1T   A[m=f2=mt*16+r][k=pi->f1]             = W2[f1][f2]
// mat 2: GEMM3  g1T = W2  @ dz2T  A[m=f1=mt*16+r][k=pi->f2]             = W2[f1][f2]
// mat 3: GEMM4  g0T = W1  @ dz1T  A[m=sigma(mt,r)][k=pi->f1]            = W1[f0][f1]
//        sigma(mt,r) = (mt&1)*32 + 8*(r>>2) + ((mt>>1)&1)*4 + (r&3)  puts each
//        lane's GEMM4 outputs on the h0 features it already holds from P0.
// stored lane-contiguous: pk[((mat*2+kt)*4+mt)*512 + lane*8 + j].
__global__ void pack_weights(const float* __restrict__ W1,
                             const float* __restrict__ W2,
                             _Float16* __restrict__ pk) {
    const int t = threadIdx.x;            // 0..63
    const int combo = blockIdx.x;         // ((mat*2+kt)*4+mt), 0..31
    const int mt  = combo & 3;
    const int kt  = (combo >> 2) & 1;
    const int mat = combo >> 3;
    const int q = t >> 4, r = t & 15;
    _Float16 v[8];
    #pragma unroll
    for (int j = 0; j < 8; ++j) {
        const int fk = (2 * kt + (j >> 2)) * 16 + 4 * q + (j & 3);   // pi(kt,q,j)
        float x;
        if (mat == 0)      x = W1[(kt * 32 + 8 * q + j) * 64 + mt * 16 + r];
        else if (mat == 1) x = W2[fk * 64 + mt * 16 + r];
        else if (mat == 2) x = W2[(mt * 16 + r) * 64 + fk];
        else {
            const int f0 = (mt & 1) * 32 + 8 * (r >> 2) + ((mt >> 1) & 1) * 4 + (r & 3);
            x = W1[f0 * 64 + fk];
        }
        v[j] = (_Float16)x;
    }
    *(half8*)(pk + combo * 512 + t * 8) = *(const half8*)v;
}

// R6 configuration — session best (151 us dispatch / 202 us bench), restored.
// NT sweep: NT=1 177us, NT=2 151us, NT=4 165us (VGPR 224, too few waves/EU).
// Persistent waves (R9): VGPR 208 -> RA settles at 2 waves/EU -> 160us. Worse.
// 2 sample-tiles per wave: two independent dependency chains interleaved at
// every phase; one ldpk weight fragment feeds 2*NT MFMAs; VGPR demand 124.
// Occupancy pinning (R2-R9 evidence: RA budget follows LDS-derived occupancy,
// not waves_per_eu attrs): 36KB pad -> 4 blocks/CU -> 4 waves/EU -> cap 128.
extern "C" __global__ void __launch_bounds__(256)
lnn_mfma(const float* __restrict__ x,
         const float* __restrict__ W0, const float* __restrict__ b0,
         const float* __restrict__ b1, const float* __restrict__ b2,
         const float* __restrict__ W3,
         const _Float16* __restrict__ pk,
         float* __restrict__ out)
{
    __shared__ float occ_pad[9216];   // 36 KB, never touched at runtime
    if (blockIdx.x == 0xFFFFFFFFu) ((volatile float*)occ_pad)[threadIdx.x] = 1.0f;

    const int t = threadIdx.x & 63;
    const int q = t >> 4;
    const int r = t & 15;
    const long sbase = (long)blockIdx.x * (64 * NT) + (threadIdx.x >> 6) * (16 * NT);

    float x0v[NT], x1v[NT];
    #pragma unroll
    for (int u = 0; u < NT; ++u) {
        const float2 xv = *(const float2*)(x + 2 * (sbase + u * 16 + r));
        x0v[u] = xv.x; x1v[u] = xv.y;
    }

    auto ldpk = [&](int mat, int kt, int mt) -> half8 {
        return *(const half8*)(pk + ((mat * 2 + kt) * 4 + mt) * 512 + t * 8);
    };

    // ---------------- P0: h0/th0 as GEMM1 B-frags (k=f0=kt*32+8q+j, n=r).
    half8 ah0[NT][2], at0[NT][2];          // [u][kt]
    #pragma unroll
    for (int kt = 0; kt < 2; ++kt) {
        const int f = kt * 32 + q * 8;
        const float4 waA = *(const float4*)(W0 + f);
        const float4 waB = *(const float4*)(W0 + f + 4);
        const float4 wbA = *(const float4*)(W0 + 64 + f);
        const float4 wbB = *(const float4*)(W0 + 64 + f + 4);
        const float4 bbA = *(const float4*)(b0 + f);
        const float4 bbB = *(const float4*)(b0 + f + 4);
        const f32x2 wa2[4] = {{waA.x,waA.y},{waA.z,waA.w},{waB.x,waB.y},{waB.z,waB.w}};
        const f32x2 wb2[4] = {{wbA.x,wbA.y},{wbA.z,wbA.w},{wbB.x,wbB.y},{wbB.z,wbB.w}};
        const f32x2 bb2[4] = {{bbA.x,bbA.y},{bbA.z,bbA.w},{bbB.x,bbB.y},{bbB.z,bbB.w}};
        #pragma unroll
        for (int u = 0; u < NT; ++u) {
            union { unsigned int uu[4]; half8 h; } ph, pt;
            #pragma unroll
            for (int p = 0; p < 4; ++p) {
                const f32x2 z = x0v[u] * wa2[p] + x1v[u] * wb2[p] + bb2[p];
                const f32x2 h = tanh2s(z * TWO_LOG2E);
                const f32x2 A = 1.0f - h * h;
                const f32x2 tt = A * wb2[p];
                ph.uu[p] = pk2(h.x, h.y);
                pt.uu[p] = pk2(tt.x, tt.y);
            }
            ah0[u][kt] = ph.h; at0[u][kt] = pt.h;
        }
    }

    // ---------------- GEMM1: z1T = W1T @ h0T  (+b1 in acc init)
    f32x4 acc[NT][4], tacc[NT][4];         // [u][mt]
    #pragma unroll
    for (int mt = 0; mt < 4; ++mt) {
        const f32x4 bv = *(const f32x4*)(b1 + mt * 16 + 4 * q);   // f1 = mt*16+4q+g
        #pragma unroll
        for (int u = 0; u < NT; ++u) {
            acc[u][mt] = bv;
            tacc[u][mt] = (f32x4){0,0,0,0};
        }
    }
    #pragma unroll
    for (int kt = 0; kt < 2; ++kt)
        #pragma unroll
        for (int mt = 0; mt < 4; ++mt) {
            const half8 aw = ldpk(0, kt, mt);      // shared by all tiles
            #pragma unroll
            for (int u = 0; u < NT; ++u) {
                acc[u][mt]  = __builtin_amdgcn_mfma_f32_16x16x32_f16(aw, ah0[u][kt], acc[u][mt], 0, 0, 0);
                tacc[u][mt] = __builtin_amdgcn_mfma_f32_16x16x32_f16(aw, at0[u][kt], tacc[u][mt], 0, 0, 0);
            }
        }

    // ---------------- P1: h1/th1 -> directly into GEMM2 B-frag words.
    // Also doubles as the h1 store P3 reads back (same positions).
    frag_u bh1[NT][2], bt1[NT][2];         // [u][kt]
    #pragma unroll
    for (int u = 0; u < NT; ++u)
        #pragma unroll
        for (int mt = 0; mt < 4; ++mt) {
            const f32x2 zp[2] = {lo2(acc[u][mt]),  hi2(acc[u][mt])};
            const f32x2 tp[2] = {lo2(tacc[u][mt]), hi2(tacc[u][mt])};
            #pragma unroll
            for (int p = 0; p < 2; ++p) {
                const f32x2 h  = tanh2s(zp[p] * TWO_LOG2E);
                const f32x2 A  = 1.0f - h * h;
                const f32x2 th = A * tp[p];
                bh1[u][mt >> 1].u[2 * (mt & 1) + p] = pk2(h.x, h.y);
                bt1[u][mt >> 1].u[2 * (mt & 1) + p] = pk2(th.x, th.y);
            }
        }

    // ---------------- GEMM2: z2T = W2T @ h1T  (+b2 in acc init)
    #pragma unroll
    for (int mt = 0; mt < 4; ++mt) {
        const f32x4 bv = *(const f32x4*)(b2 + mt * 16 + 4 * q);
        #pragma unroll
        for (int u = 0; u < NT; ++u) {
            acc[u][mt] = bv;
            tacc[u][mt] = (f32x4){0,0,0,0};
        }
    }
    #pragma unroll
    for (int kt = 0; kt < 2; ++kt)
        #pragma unroll
        for (int mt = 0; mt < 4; ++mt) {
            const half8 aw = ldpk(1, kt, mt);
            #pragma unroll
            for (int u = 0; u < NT; ++u) {
                acc[u][mt]  = __builtin_amdgcn_mfma_f32_16x16x32_f16(aw, bh1[u][kt].h, acc[u][mt], 0, 0, 0);
                tacc[u][mt] = __builtin_amdgcn_mfma_f32_16x16x32_f16(aw, bt1[u][kt].h, tacc[u][mt], 0, 0, 0);
            }
        }

    // ---------------- P2: dz2 = W3*A2 ; tdz2 = -2*h2*dz2*tz2 -> GEMM3 B-frags
    frag_u bh2[NT][2], bt2[NT][2];
    #pragma unroll
    for (int mt = 0; mt < 4; ++mt) {
        const float4 w3v = *(const float4*)(W3 + mt * 16 + 4 * q);
        const f32x2 w3p[2] = {{w3v.x, w3v.y}, {w3v.z, w3v.w}};
        #pragma unroll
        for (int u = 0; u < NT; ++u) {
            const f32x2 zp[2] = {lo2(acc[u][mt]),  hi2(acc[u][mt])};
            const f32x2 tp[2] = {lo2(tacc[u][mt]), hi2(tacc[u][mt])};
            #pragma unroll
            for (int p = 0; p < 2; ++p) {
                const f32x2 h  = tanh2s(zp[p] * TWO_LOG2E);
                const f32x2 A  = 1.0f - h * h;
                const f32x2 dz = A * w3p[p];
                const f32x2 t1 = h * tp[p];
                const f32x2 td = -2.0f * (dz * t1);
                bh2[u][mt >> 1].u[2 * (mt & 1) + p] = pk2(dz.x, dz.y);
                bt2[u][mt >> 1].u[2 * (mt & 1) + p] = pk2(td.x, td.y);
            }
        }
    }

    // ---------------- GEMM3: g1T = W2 @ dz2T
    #pragma unroll
    for (int u = 0; u < NT; ++u)
        #pragma unroll
        for (int mt = 0; mt < 4; ++mt) { acc[u][mt] = (f32x4){0,0,0,0}; tacc[u][mt] = (f32x4){0,0,0,0}; }
    #pragma unroll
    for (int kt = 0; kt < 2; ++kt)
        #pragma unroll
        for (int mt = 0; mt < 4; ++mt) {
            const half8 aw = ldpk(2, kt, mt);
            #pragma unroll
            for (int u = 0; u < NT; ++u) {
                acc[u][mt]  = __builtin_amdgcn_mfma_f32_16x16x32_f16(aw, bh2[u][kt].h, acc[u][mt], 0, 0, 0);
                tacc[u][mt] = __builtin_amdgcn_mfma_f32_16x16x32_f16(aw, bt2[u][kt].h, tacc[u][mt], 0, 0, 0);
            }
        }

    // ---------------- P3: dz1 = g1*A1 ; tdz1 = tg1*A1 - 2*g1*h1*th1
    // h1/th1 read straight back from bh1/bt1 (same (u,mt,p) positions).
    frag_u bd[NT][2], btd[NT][2];
    #pragma unroll
    for (int u = 0; u < NT; ++u)
        #pragma unroll
        for (int mt = 0; mt < 4; ++mt) {
            const f32x2 gp[2] = {lo2(acc[u][mt]),  hi2(acc[u][mt])};
            const f32x2 tp[2] = {lo2(tacc[u][mt]), hi2(tacc[u][mt])};
            #pragma unroll
            for (int p = 0; p < 2; ++p) {
                const f32x2 h  = unpk2v(bh1[u][mt >> 1].u[2 * (mt & 1) + p]);
                const f32x2 th = unpk2v(bt1[u][mt >> 1].u[2 * (mt & 1) + p]);
                const f32x2 A  = 1.0f - h * h;
                const f32x2 d1 = gp[p] * A;
                const f32x2 u2 = (gp[p] * h) * th;
                const f32x2 td = tp[p] * A + (-2.0f) * u2;
                bd[u][mt >> 1].u[2 * (mt & 1) + p]  = pk2(d1.x, d1.y);
                btd[u][mt >> 1].u[2 * (mt & 1) + p] = pk2(td.x, td.y);
            }
        }

    // ---------------- GEMM4: g0T = W1(sigma-rows) @ dz1T
    #pragma unroll
    for (int u = 0; u < NT; ++u)
        #pragma unroll
        for (int mt = 0; mt < 4; ++mt) { acc[u][mt] = (f32x4){0,0,0,0}; tacc[u][mt] = (f32x4){0,0,0,0}; }
    #pragma unroll
    for (int kt = 0; kt < 2; ++kt)
        #pragma unroll
        for (int mt = 0; mt < 4; ++mt) {
            const half8 aw = ldpk(3, kt, mt);
            #pragma unroll
            for (int u = 0; u < NT; ++u) {
                acc[u][mt]  = __builtin_amdgcn_mfma_f32_16x16x32_f16(aw, bd[u][kt].h,  acc[u][mt], 0, 0, 0);
                tacc[u][mt] = __builtin_amdgcn_mfma_f32_16x16x32_f16(aw, btd[u][kt].h, tacc[u][mt], 0, 0, 0);
            }
        }

    // ---------------- P4: with sigma, acc[u][mt][g] is the gradient for feature
    //   f0 = (mt&1)*32 + 8q + (mt>>1)*4 + g  — exactly ah0[u][mt&1] word (jb>>1)+p.
    // Recompute th0 = (1-h0^2)*wb; fold into 3 packed dots; reduce 2 shfl_xor.
    // (W0 reloaded here rather than kept from P0: holding the tables through
    //  the whole kernel costs ~32 live VGPRs and breaks the 128 cap — R9.)
    f32x2 pg2[NT], ph02[NT], ph12[NT];
    #pragma unroll
    for (int u = 0; u < NT; ++u) { pg2[u] = (f32x2){0,0}; ph02[u] = (f32x2){0,0}; ph12[u] = (f32x2){0,0}; }
    #pragma unroll
    for (int mt = 0; mt < 4; ++mt) {
        const int kt = mt & 1;
        const int jb = ((mt >> 1) & 1) * 4;          // 0 or 4
        const int f  = kt * 32 + q * 8 + jb;         // 4 consecutive features
        const float4 waF = *(const float4*)(W0 + f);
        const float4 wbF = *(const float4*)(W0 + 64 + f);
        const f32x2 wa2[2] = {{waF.x, waF.y}, {waF.z, waF.w}};
        const f32x2 wb2[2] = {{wbF.x, wbF.y}, {wbF.z, wbF.w}};
        #pragma unroll
        for (int u = 0; u < NT; ++u) {
            union { half8 h; unsigned int uu[4]; } av; av.h = ah0[u][kt];
            const unsigned int hu[2] = {av.uu[jb >> 1], av.uu[(jb >> 1) + 1]};
            const f32x2 gp[2] = {lo2(acc[u][mt]),  hi2(acc[u][mt])};
            const f32x2 tp[2] = {lo2(tacc[u][mt]), hi2(tacc[u][mt])};
            #pragma unroll
            for (int p = 0; p < 2; ++p) {
                const f32x2 h   = unpk2v(hu[p]);     // features f+2p, f+2p+1
                const f32x2 A   = 1.0f - h * h;
                const f32x2 th0 = A * wb2[p];
                const f32x2 d0  = gp[p] * A;
                const f32x2 u2  = (gp[p] * h) * th0;
                const f32x2 td0 = tp[p] * A + (-2.0f) * u2;
                pg2[u]  += wa2[p] * d0;
                ph02[u] += wa2[p] * td0;
                ph12[u] += wb2[p] * td0;
            }
        }
    }
    #pragma unroll
    for (int u = 0; u < NT; ++u) {
        float pg  = pg2[u].x  + pg2[u].y;
        float ph0 = ph02[u].x + ph02[u].y;
        float ph1 = ph12[u].x + ph12[u].y;
        pg  += __shfl_xor(pg, 16);  pg  += __shfl_xor(pg, 32);
        ph0 += __shfl_xor(ph0, 16); ph0 += __shfl_xor(ph0, 32);
        ph1 += __shfl_xor(ph1, 16); ph1 += __shfl_xor(ph1, 32);
        if (q == 0) {
            const float num = fmaf(-ph0, x1v[u], pg);
            const float den = ph1 + EPSL;
            const float a = num * __builtin_amdgcn_rcpf(den);
            float2 o;
            o.x = x1v[u];
            o.y = a;
            *(float2*)(out + 2 * (sbase + u * 16 + r)) = o;
        }
    }
}

extern "C" void kernel_launch(void* const* d_in, const int* in_sizes, int n_in,
                              void* d_out, int out_size, void* d_ws, size_t ws_size,
                              hipStream_t stream) {
    // setup_inputs order: t, x, W0, b0, W1, b1, W2, b2, W3, b3
    const float* x  = (const float*)d_in[1];
    const float* W0 = (const float*)d_in[2];
    const float* b0 = (const float*)d_in[3];
    const float* W1 = (const float*)d_in[4];
    const float* b1 = (const float*)d_in[5];
    const float* W2 = (const float*)d_in[6];
    const float* b2 = (const float*)d_in[7];
    const float* W3 = (const float*)d_in[8];
    // b3 unused (no effect on grad/Hessian)

    _Float16* pk = (_Float16*)d_ws;   // 4 mats * 4096 halfs = 32 KB
    const int B = in_sizes[1] / 2;    // 1048576

    pack_weights<<<32, 64, 0, stream>>>(W1, W2, pk);
    // 256-thread blocks = 4 waves x 32 samples (2 tiles) each
    lnn_mfma<<<B / (64 * NT), 256, 0, stream>>>(x, W0, b0, b1, b2, W3, pk, (float*)d_out);
}